// Round 19
// baseline (23.152 us; speedup 1.0000x reference)
//
#include <hip/hip_runtime.h>
#include <hip/hip_bf16.h>

#define BATCH 64
#define NADJ  512
#define F     128
#define CROP0 128
#define CROP1 384
#define CN    256
#define BN_EPS 1e-5f

typedef __attribute__((ext_vector_type(8))) short short8;
typedef __attribute__((ext_vector_type(4))) float f32x4;

__device__ __forceinline__ ushort f2bf(float x) {
  __hip_bfloat16 h = __float2bfloat16(x);  // RNE
  return *reinterpret_cast<ushort*>(&h);
}

__device__ __forceinline__ float bf2f(ushort u) {
  const unsigned v = (unsigned)u << 16;
  float f;
  __builtin_memcpy(&f, &v, 4);
  return f;
}

__device__ __forceinline__ short8 cvt8(const float4 a, const float4 b) {
  short8 r;
  r[0] = (short)f2bf(a.x); r[1] = (short)f2bf(a.y);
  r[2] = (short)f2bf(a.z); r[3] = (short)f2bf(a.w);
  r[4] = (short)f2bf(b.x); r[5] = (short)f2bf(b.y);
  r[6] = (short)f2bf(b.z); r[7] = (short)f2bf(b.w);
  return r;
}

// ---------------------------------------------------------------------------
// KA v18 (unchanged from R18 — 5 consecutive wins; frozen).
// 256 blocks x 512 threads, 1 block/CU. Block = (batch b, quarter qt),
// 4 blocks/batch on XCD (b&7). Full S[b] -> LDS stl[128][268].
// One barrier per chunk; ain dbuf; adj A-operand pre-issued + early-cvt.
// LDS: wt 34816 + ain 2x17408 + stl 68608 = 138240 B.
// ---------------------------------------------------------------------------
__global__ __launch_bounds__(512, 1) void gcn_ka(
    const float* __restrict__ input, const float* __restrict__ adj,
    const float* __restrict__ W, const float* __restrict__ beta,
    float* __restrict__ out, ushort* __restrict__ Ocrop) {
  const int x = blockIdx.x & 7, y = blockIdx.x >> 3;
  const int b  = ((y >> 2) << 3) | x;  // batch
  const int qt = y & 3;                // quarter (64 n-rows)
  __shared__ ushort wt[128][136];      // W^T [f][i]
  __shared__ ushort ain[2][64][136];   // input chunk dbuf [m][i]
  __shared__ ushort stl[128][268];     // S^T full [f][m], 536B row stride
  const int tid = threadIdx.x;
  const int l = tid & 63, w = tid >> 6;
  const int lr = l & 15, lg = l >> 4;

  // ---- pre-issue agg A-operand: 16 x float4 of adj ----
  const int n0  = qt * 64 + (w & 3) * 16;
  const int wf0 = (w >> 2) * 64;
  const float* a0 =
      adj + ((size_t)b * NADJ + CROP0 + n0 + lr) * NADJ + CROP0;
  float4 xreg[16];
#pragma unroll
  for (int ks = 0; ks < 8; ++ks) {
    const int k0 = ks * 32 + lg * 8;
    xreg[2 * ks]     = *reinterpret_cast<const float4*>(&a0[k0]);
    xreg[2 * ks + 1] = *reinterpret_cast<const float4*>(&a0[k0 + 4]);
  }

  // ---- beta-fill non-crop rows of out ----
  {
    const int gid = blockIdx.x * 512 + tid;
#pragma unroll
    for (int q = 0; q < 4; ++q) {
      const int g2 = gid + q * 131072;
      const int c4 = (g2 & 31) * 4;
      const int rr = (g2 >> 5) & 255;
      const int bb = g2 >> 13;
      const int n  = rr < 128 ? rr : rr + 256;
      const float4 bv =
          *reinterpret_cast<const float4*>(&beta[(size_t)n * F + c4]);
      *reinterpret_cast<float4*>(&out[((size_t)bb * NADJ + n) * F + c4]) = bv;
    }
  }

  // ---- stage W^T ----
  {
    const int i0 = tid & 63;
    const int fq = (tid >> 6) * 16;
#pragma unroll
    for (int ih = 0; ih < 2; ++ih) {
      const int i = i0 + ih * 64;
      const float* wr = &W[(size_t)i * F + fq];
      float4 v[4];
#pragma unroll
      for (int q = 0; q < 4; ++q)
        v[q] = reinterpret_cast<const float4*>(wr)[q];
#pragma unroll
      for (int q = 0; q < 4; ++q) {
        wt[fq + q * 4 + 0][i] = f2bf(v[q].x);
        wt[fq + q * 4 + 1][i] = f2bf(v[q].y);
        wt[fq + q * 4 + 2][i] = f2bf(v[q].z);
        wt[fq + q * 4 + 3][i] = f2bf(v[q].w);
      }
    }
  }

  // ---- issue input chunk-0 prefetch, then convert adj regs (idle slot) ----
  const float* inb = input + ((size_t)b * NADJ + CROP0) * F;
  const int msub = (w & 3) * 16;
  const int sf0  = (w >> 2) * 64;
  const int ml0  = tid >> 5;
  const int ic4  = (tid & 31) * 4;
  float4 pv[4];
#pragma unroll
  for (int q = 0; q < 4; ++q)
    pv[q] = *reinterpret_cast<const float4*>(
        &inb[(size_t)(ml0 + q * 16) * F + ic4]);

  short8 areg[8];  // adj bf16 fragments (agg A-operand), converted early
#pragma unroll
  for (int ks = 0; ks < 8; ++ks)
    areg[ks] = cvt8(xreg[2 * ks], xreg[2 * ks + 1]);

  // ---- write ain[0], single barrier ----
#pragma unroll
  for (int q = 0; q < 4; ++q)
    *reinterpret_cast<ushort4*>(&ain[0][ml0 + q * 16][ic4]) =
        make_ushort4(f2bf(pv[q].x), f2bf(pv[q].y), f2bf(pv[q].z),
                     f2bf(pv[q].w));
  __syncthreads();  // ain[0] + wt visible

  // ---- S-chunks (fully unrolled) + interleaved agg; 1 barrier/chunk ----
  f32x4 acc[4] = {};
#pragma unroll
  for (int cc = 0; cc < 4; ++cc) {
    const int mc = cc * 64;
    if (cc < 3) {
#pragma unroll
      for (int q = 0; q < 4; ++q)
        pv[q] = *reinterpret_cast<const float4*>(
            &inb[(size_t)(mc + 64 + ml0 + q * 16) * F + ic4]);
    }
    if (cc > 0) {
      const int kb0 = mc - 64;
#pragma unroll
      for (int ks2 = 0; ks2 < 2; ++ks2) {
        const int ks = (cc - 1) * 2 + ks2;  // static
        const int k0 = kb0 + ks2 * 32 + lg * 8;
#pragma unroll
        for (int fi = 0; fi < 4; ++fi) {
          const short8 bv =
              *reinterpret_cast<const short8*>(&stl[wf0 + fi * 16 + lr][k0]);
          acc[fi] = __builtin_amdgcn_mfma_f32_16x16x32_bf16(areg[ks], bv,
                                                            acc[fi], 0, 0, 0);
        }
      }
    }
    f32x4 sacc[4] = {};
#pragma unroll
    for (int ks = 0; ks < 4; ++ks) {
      const int k0 = ks * 32 + lg * 8;
      const short8 av =
          *reinterpret_cast<const short8*>(&ain[cc & 1][msub + lr][k0]);
#pragma unroll
      for (int fi = 0; fi < 4; ++fi) {
        const short8 bv =
            *reinterpret_cast<const short8*>(&wt[sf0 + fi * 16 + lr][k0]);
        sacc[fi] =
            __builtin_amdgcn_mfma_f32_16x16x32_bf16(av, bv, sacc[fi], 0, 0, 0);
      }
    }
#pragma unroll
    for (int fi = 0; fi < 4; ++fi)
      *reinterpret_cast<ushort4*>(
          &stl[sf0 + fi * 16 + lr][mc + msub + lg * 4]) =
          make_ushort4(f2bf(sacc[fi][0]), f2bf(sacc[fi][1]),
                       f2bf(sacc[fi][2]), f2bf(sacc[fi][3]));
    if (cc < 3) {
#pragma unroll
      for (int q = 0; q < 4; ++q)
        *reinterpret_cast<ushort4*>(&ain[(cc + 1) & 1][ml0 + q * 16][ic4]) =
            make_ushort4(f2bf(pv[q].x), f2bf(pv[q].y), f2bf(pv[q].z),
                         f2bf(pv[q].w));
    }
    __syncthreads();  // stl chunk cc + ain[(cc+1)&1] visible
  }

  // ---- final agg chunk (k 192..255) ----
#pragma unroll
  for (int ks2 = 0; ks2 < 2; ++ks2) {
    const int ks = 6 + ks2;
    const int k0 = 192 + ks2 * 32 + lg * 8;
#pragma unroll
    for (int fi = 0; fi < 4; ++fi) {
      const short8 bv =
          *reinterpret_cast<const short8*>(&stl[wf0 + fi * 16 + lr][k0]);
      acc[fi] = __builtin_amdgcn_mfma_f32_16x16x32_bf16(areg[ks], bv, acc[fi],
                                                        0, 0, 0);
    }
  }

  // ---- store Ocrop (bf16): col(f)=lane&15, row(n)=4*(lane>>4)+reg ----
#pragma unroll
  for (int fi = 0; fi < 4; ++fi) {
    const int f = wf0 + fi * 16 + lr;
    const int n = n0 + lg * 4;
#pragma unroll
    for (int r = 0; r < 4; ++r)
      Ocrop[((size_t)b * CN + n + r) * F + f] = f2bf(acc[fi][r]);
  }
}

// ---------------------------------------------------------------------------
// KB v19: vectorized x4. 256 blocks x 256 threads.
// Thread = (feature-quad qq = tid&31 of block's 32, batch-group bg = tid>>5
// of 8 batches). ushort4 Ocrop loads, float4 out stores, f32x4 LDS reduce.
// ---------------------------------------------------------------------------
__global__ __launch_bounds__(256) void gcn_kb(
    const ushort* __restrict__ Ocrop, float* __restrict__ out,
    const float* __restrict__ gamma, const float* __restrict__ beta) {
  __shared__ f32x4 s_l[256], s2_l[256];  // 8 KB
  __shared__ f32x4 m_l[32], r_l[32];
  const int tid = threadIdx.x;
  const int qq = tid & 31, bg = tid >> 5;
  const int j  = (blockIdx.x * 32 + qq) * 4;  // feature id nl*128+f, f%4==0
  const int nl = j >> 7, f = j & 127;
  const int nf = (CROP0 + nl) * F + f;
  const ushort* p = Ocrop + (size_t)j + (size_t)bg * 8 * CN * F;

  f32x4 x[8];
  f32x4 s = {0.f, 0.f, 0.f, 0.f}, s2 = {0.f, 0.f, 0.f, 0.f};
#pragma unroll
  for (int bb = 0; bb < 8; ++bb) {
    const ushort4 u =
        *reinterpret_cast<const ushort4*>(&p[(size_t)bb * CN * F]);
    f32x4 v;
    v[0] = bf2f(u.x); v[1] = bf2f(u.y); v[2] = bf2f(u.z); v[3] = bf2f(u.w);
    x[bb] = v;
    s += v;
    s2 += v * v;
  }
  s_l[tid]  = s;
  s2_l[tid] = s2;
  __syncthreads();
  if (tid < 32) {
    f32x4 ts = {0.f, 0.f, 0.f, 0.f}, ts2 = {0.f, 0.f, 0.f, 0.f};
#pragma unroll
    for (int g = 0; g < 8; ++g) {
      ts += s_l[g * 32 + tid];
      ts2 += s2_l[g * 32 + tid];
    }
    const f32x4 mean = ts * (1.f / BATCH);
    const f32x4 var  = ts2 * (1.f / BATCH) - mean * mean;
    f32x4 rs;
    rs[0] = rsqrtf(var[0] + BN_EPS);
    rs[1] = rsqrtf(var[1] + BN_EPS);
    rs[2] = rsqrtf(var[2] + BN_EPS);
    rs[3] = rsqrtf(var[3] + BN_EPS);
    m_l[tid] = mean;
    r_l[tid] = rs;
  }
  __syncthreads();
  const f32x4 mean = m_l[qq];
  const f32x4 rs   = r_l[qq];
  const float4 gm = *reinterpret_cast<const float4*>(&gamma[nf]);
  const float4 bt = *reinterpret_cast<const float4*>(&beta[nf]);
  f32x4 a, c;
  a[0] = rs[0] * gm.x; a[1] = rs[1] * gm.y;
  a[2] = rs[2] * gm.z; a[3] = rs[3] * gm.w;
  c[0] = bt.x - mean[0] * a[0]; c[1] = bt.y - mean[1] * a[1];
  c[2] = bt.z - mean[2] * a[2]; c[3] = bt.w - mean[3] * a[3];
#pragma unroll
  for (int bb = 0; bb < 8; ++bb) {
    const f32x4 y = x[bb] * a + c;
    *reinterpret_cast<f32x4*>(
        &out[(size_t)nf + (size_t)(bg * 8 + bb) * NADJ * F]) = y;
  }
}

extern "C" void kernel_launch(void* const* d_in, const int* in_sizes, int n_in,
                              void* d_out, int out_size, void* d_ws,
                              size_t ws_size, hipStream_t stream) {
  const float* input = (const float*)d_in[0];
  const float* adj   = (const float*)d_in[1];
  const float* W     = (const float*)d_in[2];
  const float* gamma = (const float*)d_in[3];
  const float* beta  = (const float*)d_in[4];
  float* out = (float*)d_out;

  ushort* Ocrop = (ushort*)d_ws;  // 64*256*128 bf16 = 4.2 MB

  gcn_ka<<<256, 512, 0, stream>>>(input, adj, W, beta, out, Ocrop);
  gcn_kb<<<256, 256, 0, stream>>>(Ocrop, out, gamma, beta);
}